// Round 4
// baseline (1667.916 us; speedup 1.0000x reference)
//
#include <hip/hip_runtime.h>
#include <hip/hip_fp16.h>
#include <cmath>

typedef unsigned short u16;
typedef unsigned int   u32;

// Problem constants
constexpr int B_ = 8, T_ = 32, N_ = 24, D_ = 128;
constexpr int BT_ = B_ * T_;            // 256
constexpr int VW_ = N_ * N_;            // 576
constexpr int BTN_ = BT_ * N_;          // 6144
constexpr int BTVW_ = BT_ * VW_;        // 147456
constexpr int P_ = 3;
constexpr int C_ = 6;

__device__ __forceinline__ float bits2f(u32 u) { float f; __builtin_memcpy(&f, &u, 4); return f; }
__device__ __forceinline__ float bf2f(u16 h) { return bits2f(((u32)h) << 16); }
__device__ __forceinline__ u16 f2bf(float f) {
    u32 u; __builtin_memcpy(&u, &f, 4);
    u32 r = u + 0x7FFFu + ((u >> 16) & 1u);
    return (u16)(r >> 16);
}
__device__ __forceinline__ float h2f(u16 b) {
    __half h; __builtin_memcpy(&h, &b, 2);
    return __half2float(h);
}
__device__ __forceinline__ float sigm(float x) { return 1.0f / (1.0f + expf(-x)); }

// flag: 0 = bf16, 1 = fp32, 2 = fp16
__device__ __forceinline__ float ldany(const void* p, size_t i, int flg) {
    if (flg == 1) return ((const float*)p)[i];
    if (flg == 0) return bf2f(((const u16*)p)[i]);
    return h2f(((const u16*)p)[i]);
}

// ---------------------------------------------------------------------------
// Dtype detection: node_resnet [bt,d,n] has zeros exactly at n >= nnr[bt].
// Score 3 interpretations over 768 probe points; write argmax to flag.
// ---------------------------------------------------------------------------
__global__ __launch_bounds__(256) void k_detect(const void* __restrict__ node,
                                                const int* __restrict__ nnr,
                                                int* __restrict__ flag) {
    __shared__ int sc[3];
    const int tid = threadIdx.x;
    if (tid < 3) sc[tid] = 0;
    __syncthreads();
    int loc0 = 0, loc1 = 0, loc2 = 0;
    for (int c = tid; c < 768; c += 256) {
        const int bt = c / 96, rem = c % 96;
        const int d = rem / 24, n = rem % 24;
        const bool ez = (n >= nnr[bt]);
        const size_t i = (size_t)bt * 3072 + d * 24 + n;
        {
            const float v = bf2f(((const u16*)node)[i]);
            loc0 += (ez ? (v == 0.0f) : (v != 0.0f && fabsf(v) < 100.0f)) ? 1 : 0;
        }
        {
            const float v = ((const float*)node)[i];
            loc1 += (isfinite(v) && (ez ? (v == 0.0f) : (v != 0.0f && fabsf(v) < 100.0f))) ? 1 : 0;
        }
        {
            const float v = h2f(((const u16*)node)[i]);
            loc2 += (isfinite(v) && (ez ? (v == 0.0f) : (v != 0.0f && fabsf(v) < 100.0f))) ? 1 : 0;
        }
    }
    atomicAdd(&sc[0], loc0);
    atomicAdd(&sc[1], loc1);
    atomicAdd(&sc[2], loc2);
    __syncthreads();
    if (tid == 0) {
        int f = 0, best = sc[0];
        if (sc[1] > best) { f = 1; best = sc[1]; }
        if (sc[2] > best) { f = 2; }
        flag[0] = f;
    }
}

// ---------------------------------------------------------------------------
// Canonicalize a weight/bias array to bf16 in ws (identity copy when flg==0).
// ---------------------------------------------------------------------------
__global__ __launch_bounds__(256) void k_convw(const void* __restrict__ src, u16* __restrict__ dst,
                                               int n, const int* __restrict__ flag) {
    const int i = blockIdx.x * 256 + threadIdx.x;
    if (i >= n) return;
    const int flg = flag[0];
    if (flg == 0) { dst[i] = ((const u16*)src)[i]; return; }
    dst[i] = f2bf(flg == 1 ? ((const float*)src)[i] : h2f(((const u16*)src)[i]));
}

// Shared 4-row x 4-col register-tile GEMM over K=128.
// xs: rows of X (row stride 128 floats); Wc: swizzled bf16 weights
// (Wc[dc*512 + oj*128 + og*4 + dj] = W[(og*4+oj)*128 + dc*4 + dj]).
__device__ __forceinline__ void tile_gemm(const float* xs, const u16* Wc,
                                          int og, int rg, float acc[4][4]) {
#pragma unroll
    for (int r = 0; r < 4; ++r)
#pragma unroll
        for (int oj = 0; oj < 4; ++oj) acc[r][oj] = 0.0f;
    for (int dc = 0; dc < 32; ++dc) {
        float4 xv[4];
#pragma unroll
        for (int r = 0; r < 4; ++r) xv[r] = *(const float4*)&xs[(rg * 4 + r) * 128 + dc * 4];
#pragma unroll
        for (int oj = 0; oj < 4; ++oj) {
            const uint2 wu = *(const uint2*)&Wc[dc * 512 + oj * 128 + og * 4];
            const float w0 = bits2f(wu.x << 16), w1 = bits2f(wu.x & 0xFFFF0000u);
            const float w2f = bits2f(wu.y << 16), w3 = bits2f(wu.y & 0xFFFF0000u);
#pragma unroll
            for (int r = 0; r < 4; ++r)
                acc[r][oj] = fmaf(xv[r].w, w3,
                             fmaf(xv[r].z, w2f,
                             fmaf(xv[r].y, w1,
                             fmaf(xv[r].x, w0, acc[r][oj]))));
        }
    }
}

// ---------------------------------------------------------------------------
// Transpose node_resnet [bt, d, n] -> HN [bt, n, d] fp32. grid = BT_
// ---------------------------------------------------------------------------
__global__ __launch_bounds__(256) void k_transpose_node(const void* __restrict__ node,
                                                        float* __restrict__ HN,
                                                        const int* __restrict__ flag) {
    const int bt = blockIdx.x;
    const int flg = flag[0];
    for (int f = threadIdx.x; f < 3072; f += 256) {
        const int d = f / 24, n = f - d * 24;
        HN[(size_t)bt * 3072 + n * 128 + d] = ldany(node, (size_t)bt * 3072 + f, flg);
    }
}

// ---------------------------------------------------------------------------
// LSTM weight transpose (canonical bf16 in): WT[kk*1024+j*2+p] = W[j*128+kk*2+p]
// ---------------------------------------------------------------------------
__global__ __launch_bounds__(256) void k_wtprep(const u16* __restrict__ Wih, const u16* __restrict__ Whh,
                                                u16* __restrict__ WTih, u16* __restrict__ WThh) {
    const int idx = blockIdx.x * 256 + threadIdx.x;
    const int kk = idx >> 10;
    const int rem = idx & 1023;
    const int j = rem >> 1, p = rem & 1;
    WTih[idx] = Wih[j * 128 + kk * 2 + p];
    WThh[idx] = Whh[j * 128 + kk * 2 + p];
}

// ---------------------------------------------------------------------------
// XW = msg_Wh @ h_node. 192 blocks x 32 rows, 256 threads (4x4 tiles).
// ---------------------------------------------------------------------------
__global__ __launch_bounds__(256) void k_xw(const float* __restrict__ HN, const u16* __restrict__ W,
                                            float* __restrict__ XW) {
    __shared__ __align__(16) u16 Wc[16384];
    __shared__ __align__(16) float xs[4096];
    const int tid = threadIdx.x;
    const int og = tid & 31, rg = tid >> 5;
    for (int f = tid; f < 16384; f += 256) {
        const int dj = f & 3, o_g = (f >> 2) & 31, oj = (f >> 7) & 3, dc = f >> 9;
        Wc[f] = W[((o_g * 4 + oj) << 7) + (dc << 2) + dj];
    }
    const int rowBase = blockIdx.x * 32;
    for (int f = tid; f < 4096; f += 256) xs[f] = HN[(size_t)rowBase * 128 + f];
    __syncthreads();
    float acc[4][4];
    tile_gemm(xs, Wc, og, rg, acc);
#pragma unroll
    for (int r = 0; r < 4; ++r) {
        const int row = rowBase + rg * 4 + r;
        float4 o4;
        o4.x = acc[r][0]; o4.y = acc[r][1]; o4.z = acc[r][2]; o4.w = acc[r][3];
        *(float4*)&XW[(size_t)row * 128 + og * 4] = o4;
    }
}

// ---------------------------------------------------------------------------
// Unified per-(bt,v) edge kernel. 192 threads = 32 og-lanes x 6 row-groups.
//  DO_MSG: me = We @ e_vw (raw); gv = sigm(adj)*relu(xw_w + me + mb) for valid
//          pairs (else keep raw row -> h_edge); MV[v] = sum_w gv.
//  DO_ADJ: adj' = W2 . relu(W1 @ xs + b1) + b2 over current xs rows.
// ---------------------------------------------------------------------------
template <bool DO_MSG, bool DO_ADJ>
__global__ __launch_bounds__(192) void k_edge(
    const void* __restrict__ edge, const int* __restrict__ flag,
    const float* __restrict__ XW,
    const u16* __restrict__ We, const u16* __restrict__ msgb,
    const u16* __restrict__ W1, const u16* __restrict__ b1,
    const u16* __restrict__ W2, const u16* __restrict__ b2,
    const int* __restrict__ nnr, float* __restrict__ ADJ,
    float* __restrict__ MV) {
    __shared__ __align__(16) u16 Wc[16384];
    __shared__ __align__(16) float xs[24 * 128];
    __shared__ __align__(16) float xw_s[24 * 128];
    __shared__ float mb_s[128];
    __shared__ float b1_s[128];
    __shared__ float w2_s[128];
    __shared__ float gate_s[24];
    const int tid = threadIdx.x;
    const int og = tid & 31, rg = tid >> 5;   // rg 0..5
    const int blk = blockIdx.x;
    const int bt = blk / N_, v = blk - bt * N_;
    const int nv = nnr[bt];
    const int flg = flag[0];
    const size_t rowbase = (size_t)bt * VW_ + (size_t)v * N_;
    const size_t ebase = (size_t)bt * D_ * VW_ + (size_t)v * N_;

    // stage raw edge rows, d-major walk for coalescing: xs[w*128+d]
    if (flg == 1) {
        for (int f = tid; f < 3072; f += 192) {
            const int d = f / 24, w = f - d * 24;
            xs[w * 128 + d] = ((const float*)edge)[ebase + (size_t)d * VW_ + w];
        }
    } else if (flg == 0) {
        for (int f = tid; f < 3072; f += 192) {
            const int d = f / 24, w = f - d * 24;
            xs[w * 128 + d] = bf2f(((const u16*)edge)[ebase + (size_t)d * VW_ + w]);
        }
    } else {
        for (int f = tid; f < 3072; f += 192) {
            const int d = f / 24, w = f - d * 24;
            xs[w * 128 + d] = h2f(((const u16*)edge)[ebase + (size_t)d * VW_ + w]);
        }
    }
    const u16* W0 = DO_MSG ? We : W1;
    for (int f = tid; f < 16384; f += 192) {
        const int dj = f & 3, o_g = (f >> 2) & 31, oj = (f >> 7) & 3, dc = f >> 9;
        Wc[f] = W0[((o_g * 4 + oj) << 7) + (dc << 2) + dj];
    }
    if constexpr (DO_MSG) {
        for (int f = tid; f < 3072; f += 192) xw_s[f] = XW[(size_t)bt * N_ * 128 + f];
        if (tid < 128) mb_s[tid] = bf2f(msgb[tid]);
        if (tid < 24) gate_s[tid] = sigm(ADJ[rowbase + tid]);
    }
    if constexpr (DO_ADJ) {
        if (tid < 128) { b1_s[tid] = bf2f(b1[tid]); w2_s[tid] = bf2f(W2[tid]); }
    }
    __syncthreads();

    if constexpr (DO_MSG) {
        float acc[4][4];
        tile_gemm(xs, Wc, og, rg, acc);
        const bool vvalid = v < nv;
        // overwrite valid cells of xs with gated messages (each thread touches
        // only rows of its own row-group, read before write within the thread)
#pragma unroll
        for (int r = 0; r < 4; ++r) {
            const int w = rg * 4 + r;
            if (vvalid && w < nv) {
#pragma unroll
                for (int oj = 0; oj < 4; ++oj) {
                    const int o = og * 4 + oj;
                    float m = xw_s[w * 128 + o] + acc[r][oj] + mb_s[o];
                    m = fmaxf(m, 0.0f);
                    xs[w * 128 + o] = gate_s[w] * m;
                }
            }
        }
        __syncthreads();
        if (tid < 128) {
            float s = 0.0f;
            if (vvalid)
                for (int w = 0; w < nv; ++w) s += xs[w * 128 + tid];
            MV[(size_t)blk * 128 + tid] = s;
        }
        if constexpr (DO_ADJ) {
            for (int f = tid; f < 16384; f += 192) {
                const int dj = f & 3, o_g = (f >> 2) & 31, oj = (f >> 7) & 3, dc = f >> 9;
                Wc[f] = W1[((o_g * 4 + oj) << 7) + (dc << 2) + dj];
            }
            __syncthreads();
        }
    }

    if constexpr (DO_ADJ) {
        float a2[4][4];
        tile_gemm(xs, Wc, og, rg, a2);
        const float b2v = bf2f(b2[0]);
#pragma unroll
        for (int r = 0; r < 4; ++r) {
            float p = 0.0f;
#pragma unroll
            for (int oj = 0; oj < 4; ++oj) {
                const int o = og * 4 + oj;
                float h = a2[r][oj] + b1_s[o];
                h = fmaxf(h, 0.0f);
                p += h * w2_s[o];
            }
#pragma unroll
            for (int off = 16; off > 0; off >>= 1) p += __shfl_down(p, off);
            if (og == 0) ADJ[rowbase + rg * 4 + r] = p + b2v;
        }
    }
}

// ---------------------------------------------------------------------------
// Fused GRU: 32 nodes/block, 256 threads (4x4 tile). Per gate: stage Wih_g
// then Whh_g in LDS, accumulate, combine. Invalid nodes -> 0 (== node_resnet).
// ---------------------------------------------------------------------------
__global__ __launch_bounds__(256) void k_gru(
    const float* __restrict__ MV, const u16* __restrict__ Wih, const u16* __restrict__ Whh,
    const u16* __restrict__ bih, const u16* __restrict__ bhh,
    const int* __restrict__ nnr, float* __restrict__ HN) {
    __shared__ __align__(16) u16 Wc[16384];
    __shared__ __align__(16) float xs[32 * 128];
    __shared__ __align__(16) float hs[32 * 128];
    const int tid = threadIdx.x;
    const int og = tid & 31, rg = tid >> 5;   // rg 0..7
    const int node0 = blockIdx.x * 32;
    for (int f = tid; f < 4096; f += 256) {
        xs[f] = MV[(size_t)node0 * 128 + f];
        hs[f] = HN[(size_t)node0 * 128 + f];
    }
    float rr[4][4], zz[4][4], nn[4][4];
    for (int g = 0; g < 3; ++g) {
        float gi[4][4], gh[4][4];
        for (int half = 0; half < 2; ++half) {
            __syncthreads();   // protects Wc (and first-iter xs/hs staging)
            const u16* Wsrc = (half == 0 ? Wih : Whh) + g * 16384;
            for (int f = tid; f < 16384; f += 256) {
                const int dj = f & 3, o_g = (f >> 2) & 31, oj = (f >> 7) & 3, dc = f >> 9;
                Wc[f] = Wsrc[((o_g * 4 + oj) << 7) + (dc << 2) + dj];
            }
            __syncthreads();
            float a[4][4];
            tile_gemm(half == 0 ? xs : hs, Wc, og, rg, a);
#pragma unroll
            for (int r = 0; r < 4; ++r)
#pragma unroll
                for (int oj = 0; oj < 4; ++oj) {
                    if (half == 0) gi[r][oj] = a[r][oj];
                    else           gh[r][oj] = a[r][oj];
                }
        }
#pragma unroll
        for (int r = 0; r < 4; ++r)
#pragma unroll
            for (int oj = 0; oj < 4; ++oj) {
                const int o = og * 4 + oj;
                const float giv = gi[r][oj] + bf2f(bih[g * 128 + o]);
                const float ghv = gh[r][oj] + bf2f(bhh[g * 128 + o]);
                if (g == 0) rr[r][oj] = sigm(giv + ghv);
                else if (g == 1) zz[r][oj] = sigm(giv + ghv);
                else nn[r][oj] = tanhf(giv + rr[r][oj] * ghv);
            }
    }
#pragma unroll
    for (int r = 0; r < 4; ++r) {
        const int row = rg * 4 + r;
        const int node = node0 + row;
        const int bt = node / N_, vv = node - bt * N_;
        const int nv = nnr[bt];
#pragma unroll
        for (int oj = 0; oj < 4; ++oj) {
            const int o = og * 4 + oj;
            const float h = hs[row * 128 + o];
            const float hv = (1.0f - zz[r][oj]) * nn[r][oj] + zz[r][oj] * h;
            HN[(size_t)node * 128 + o] = (vv < nv) ? hv : 0.0f;
        }
    }
}

// ---------------------------------------------------------------------------
// Full temporal LSTM, rows independent: 96 blocks x 2 rows, 512 threads.
// ---------------------------------------------------------------------------
__global__ __launch_bounds__(512) void k_lstm(const float* __restrict__ HN, const u16* __restrict__ WTih,
                                              const u16* __restrict__ WThh, const u16* __restrict__ bih,
                                              const u16* __restrict__ bhh, float* __restrict__ OUTH) {
    __shared__ __align__(16) float x_lds[2][128];
    __shared__ __align__(16) float h_lds[2][128];
    __shared__ __align__(16) float Glds[2][512];
    const int tid = threadIdx.x;
    const float biasj = bf2f(bih[tid]) + bf2f(bhh[tid]);
    const int rw = tid >> 7, idx = tid & 127;  // valid when tid<256
    float c = 0.0f;
    if (tid < 256) h_lds[rw][idx] = 0.0f;
    const int r0 = blockIdx.x * 2;
    __syncthreads();
    for (int t = 0; t < T_; ++t) {
        if (tid < 256) {
            const int rr = r0 + rw;
            const int bb = rr / N_, n2 = rr - bb * N_;
            x_lds[rw][idx] = HN[(((size_t)bb * T_ + t) * N_ + n2) * 128 + idx];
        }
        __syncthreads();
        float a0 = 0.0f, a1 = 0.0f;
        for (int kk = 0; kk < 64; ++kk) {
            const u32 wi = *(const u32*)&WTih[kk * 1024 + tid * 2];
            const u32 wh = *(const u32*)&WThh[kk * 1024 + tid * 2];
            const float wi0 = bits2f(wi << 16), wi1 = bits2f(wi & 0xFFFF0000u);
            const float wh0 = bits2f(wh << 16), wh1 = bits2f(wh & 0xFFFF0000u);
            const float2 xa = *(const float2*)&x_lds[0][kk * 2];
            const float2 xb = *(const float2*)&x_lds[1][kk * 2];
            const float2 ha = *(const float2*)&h_lds[0][kk * 2];
            const float2 hb = *(const float2*)&h_lds[1][kk * 2];
            a0 += wi0 * xa.x + wi1 * xa.y + wh0 * ha.x + wh1 * ha.y;
            a1 += wi0 * xb.x + wi1 * xb.y + wh0 * hb.x + wh1 * hb.y;
        }
        Glds[0][tid] = a0 + biasj;
        Glds[1][tid] = a1 + biasj;
        __syncthreads();
        if (tid < 256) {
            const float gi = Glds[rw][idx], gf = Glds[rw][128 + idx];
            const float gg = Glds[rw][256 + idx], go = Glds[rw][384 + idx];
            c = sigm(gf) * c + sigm(gi) * tanhf(gg);
            const float hv = sigm(go) * tanhf(c);
            h_lds[rw][idx] = hv;
            OUTH[((size_t)t * 192 + r0 + rw) * 128 + idx] = hv;
        }
        __syncthreads();
    }
}

// ---------------------------------------------------------------------------
// Readout: out[b,t,n,c] = mask ? OUTH_row . ro_W[c] + ro_b[c] : 0
// Output dtype matches detected input dtype.
// ---------------------------------------------------------------------------
__global__ __launch_bounds__(256) void k_readout(const float* __restrict__ OUTH, const u16* __restrict__ roW,
                                                 const u16* __restrict__ rob, const int* __restrict__ nnr,
                                                 void* __restrict__ out, const int* __restrict__ flag) {
    const int idx = blockIdx.x * 256 + threadIdx.x;
    const int btn = idx / C_, c = idx - btn * C_;
    const int bt = btn / N_, n = btn - bt * N_;
    const int b = bt / T_, t = bt - b * T_;
    const int nv = nnr[bt];
    float val = 0.0f;
    if (n < nv) {
        const float* hrow = OUTH + ((size_t)t * 192 + b * N_ + n) * 128;
        float acc = bf2f(rob[c]);
        for (int k = 0; k < 128; ++k) acc += bf2f(roW[c * 128 + k]) * hrow[k];
        val = acc;
    }
    const int flg = flag[0];
    if (flg == 1) ((float*)out)[idx] = val;
    else if (flg == 0) ((u16*)out)[idx] = f2bf(val);
    else { __half h = __float2half(val); u16 b16; __builtin_memcpy(&b16, &h, 2); ((u16*)out)[idx] = b16; }
}

// ---------------------------------------------------------------------------
extern "C" void kernel_launch(void* const* d_in, const int* in_sizes, int n_in,
                              void* d_out, int out_size, void* d_ws, size_t ws_size,
                              hipStream_t stream) {
    const void* node = d_in[0];
    const void* edge = d_in[1];
    const int* nnr = (const int*)d_in[19];

    // Workspace layout (~11 MB)
    char* ws = (char*)d_ws;
    int* dflag = (int*)ws;    ws += 16;
    float* HN = (float*)ws;   ws += (size_t)BTN_ * D_ * 4;    // 3.15 MB
    float* XW = (float*)ws;   ws += (size_t)BTN_ * D_ * 4;    // 3.15 MB
    float* MV = (float*)ws;   ws += (size_t)BTN_ * D_ * 4;    // 3.15 MB
    float* ADJ = (float*)ws;  ws += (size_t)BTVW_ * 4;        // 0.59 MB
    u16* WTih = (u16*)ws;     ws += 65536 * 2;
    u16* WThh = (u16*)ws;     ws += 65536 * 2;
    float* OUTH = XW;         // XW dead after last k_edge; same size

    // Canonical bf16 weight arrays (converted from whatever dtype inputs are)
    u16* cbase = (u16*)ws;
    const int cvtN[17] = {16384, 128, 128, 1, 16384, 16384, 128,
                          49152, 49152, 384, 384, 65536, 65536, 512, 512, 768, 6};
    u16* cptr[17];
    {
        size_t off = 0;
        for (int i = 0; i < 17; ++i) {
            cptr[i] = cbase + off;
            off += (size_t)((cvtN[i] + 7) & ~7);
        }
    }
    u16* cW1 = cptr[0];  u16* cb1 = cptr[1];  u16* cW2 = cptr[2];  u16* cb2 = cptr[3];
    u16* cWh = cptr[4];  u16* cWe = cptr[5];  u16* cmb = cptr[6];
    u16* cgWih = cptr[7]; u16* cgWhh = cptr[8]; u16* cgbih = cptr[9]; u16* cgbhh = cptr[10];
    u16* clsWih = cptr[11]; u16* clsWhh = cptr[12]; u16* clsbih = cptr[13]; u16* clsbhh = cptr[14];
    u16* croW = cptr[15]; u16* crob = cptr[16];

    // 1. detect input float dtype
    k_detect<<<1, 256, 0, stream>>>(node, nnr, dflag);
    // 2. canonicalize weights to bf16 (inputs 2..18)
    for (int i = 0; i < 17; ++i) {
        const int n = cvtN[i];
        k_convw<<<(n + 255) / 256, 256, 0, stream>>>(d_in[2 + i], cptr[i], n, dflag);
    }
    // 3. node transpose -> fp32 HN
    k_transpose_node<<<BT_, 256, 0, stream>>>(node, HN, dflag);
    k_wtprep<<<256, 256, 0, stream>>>(clsWih, clsWhh, WTih, WThh);
    // 4. layer-0 adjacency logits from raw edge features
    k_edge<false, true><<<BTN_, 192, 0, stream>>>(edge, dflag, XW, cWe, cmb, cW1, cb1, cW2, cb2,
                                                  nnr, ADJ, MV);
    for (int l = 0; l < P_; ++l) {
        k_xw<<<192, 256, 0, stream>>>(HN, cWh, XW);
        if (l < P_ - 1)
            k_edge<true, true><<<BTN_, 192, 0, stream>>>(edge, dflag, XW, cWe, cmb, cW1, cb1, cW2, cb2,
                                                         nnr, ADJ, MV);
        else
            k_edge<true, false><<<BTN_, 192, 0, stream>>>(edge, dflag, XW, cWe, cmb, cW1, cb1, cW2, cb2,
                                                          nnr, ADJ, MV);
        k_gru<<<192, 256, 0, stream>>>(MV, cgWih, cgWhh, cgbih, cgbhh, nnr, HN);
    }
    k_lstm<<<96, 512, 0, stream>>>(HN, WTih, WThh, clsbih, clsbhh, OUTH);
    k_readout<<<144, 256, 0, stream>>>(OUTH, croW, crob, nnr, d_out, dflag);
}